// Round 11
// baseline (142.140 us; speedup 1.0000x reference)
//
#include <hip/hip_runtime.h>

// LinkPredictor: out[e] = W2 . relu(W1s.z[src] + W1d.z[dst] + b1) + b2
// Factored: C = z @ [W1s|W1d]^T  (node GEMM, bf16 MFMA), then per-edge
// gather + fused add/relu/dot.
// GEMM v11 = v10 + dual-slot ILP: each wave interleaves TWO independent
// 32-node slots at k-step granularity, doubling the issue->use distance
// of the z prefetch (~2 super-steps ~= HBM latency) and the number of
// independent load chains per SIMD. Wt quarter in LDS (64 KB swizzled,
// one barrier); z loads early-issued under the stage phase.

#define NN 100000   // nodes (3125 slots of 32, exact)
#define NE 300000   // edges
#define KD 256      // in channels (K)
#define NO 512      // 2*HID output cols (A | B)
#define NBLK 1568   // gemm blocks; streams = 1568*4/4quarters = 1568

typedef __attribute__((ext_vector_type(8))) short short8;
typedef __attribute__((ext_vector_type(8))) unsigned short ushort8;
typedef __attribute__((ext_vector_type(4))) float f32x4;
typedef __attribute__((ext_vector_type(4))) unsigned int uint4v;

__device__ __forceinline__ unsigned short f2bf(float f) {
  union { float f; unsigned int u; } v; v.f = f;
  unsigned int u = v.u;
  u += 0x7fffu + ((u >> 16) & 1u);   // RNE
  return (unsigned short)(u >> 16);
}
__device__ __forceinline__ float bf2f(unsigned short h) {
  union { unsigned int u; float f; } v; v.u = ((unsigned int)h) << 16;
  return v.f;
}
// pack 2 f32 -> {bf16(a) low, bf16(b) high} (round-half-up)
__device__ __forceinline__ unsigned int pkbf(float a, float b) {
  unsigned int ua = __float_as_uint(a) + 0x8000u;
  unsigned int ub = __float_as_uint(b) + 0x8000u;
  return __builtin_amdgcn_perm(ub, ua, 0x07060302u);
}

// ---- repack W1 (f32 [256][512]) -> Wt (bf16 [512][256], K-contiguous) ----
__global__ void prep_w(const float* __restrict__ W1, unsigned short* __restrict__ Wt) {
  int idx = blockIdx.x * 256 + threadIdx.x;   // 512*256 = 131072
  int j = idx >> 8, k = idx & 255;
  float v = (j < 256) ? W1[j * 512 + k] : W1[(j - 256) * 512 + 256 + k];
  Wt[idx] = f2bf(v);
}

// ---- C[n][j] = sum_k z[n][k] * Wt[j][k]  (natural layout) ----
__global__ __launch_bounds__(256, 2) void gemm_zw(const float* __restrict__ z,
                                                  const unsigned short* __restrict__ Wt,
                                                  unsigned short* __restrict__ C) {
  __shared__ unsigned short Bs[128 * KD];   // 64 KB: Wt quarter, swizzled

  // XCD-pinned: 4 quarter-siblings share blockIdx&7 (same XCD)
  const int b = blockIdx.x;            // 0..1567
  const int xcd = b & 7;
  const int rr = b >> 3;               // 0..195
  const int q = rr & 3;                // col quarter
  const int gg = (rr >> 2) * 8 + xcd;  // 0..391
  const int n0 = q * 128;

  const int t = threadIdx.x;
  const int w = t >> 6, lane = t & 63;
  const int l15 = lane & 15, l4 = lane >> 4;

  const int sigma = gg * 4 + w;        // wave stream 0..1567
  const int sA = sigma;
  const int sB = sigma + NBLK;
  const bool dual = (sB < 3125);       // slots cover 0..3124 exactly once

  const float* zrA = z + (size_t)(sA * 32 + l15) * KD + l4 * 8;
  const float* zrB = z + (size_t)(sB * 32 + l15) * KD + l4 * 8;

#define LOADZ(ZP, kc, Ra, Rb, Rc, Rd)                              \
  Ra = *(const float4*)((ZP) + (kc) * 32);                         \
  Rb = *(const float4*)((ZP) + (kc) * 32 + 4);                     \
  Rc = *(const float4*)((ZP) + 16 * KD + (kc) * 32);               \
  Rd = *(const float4*)((ZP) + 16 * KD + (kc) * 32 + 4);

  float4 ZA0a, ZA0b, ZA0c, ZA0d, ZA1a, ZA1b, ZA1c, ZA1d;
  float4 ZB0a, ZB0b, ZB0c, ZB0d, ZB1a, ZB1b, ZB1c, ZB1d;

  // early z prefetch: issue before the stage phase so HBM latency hides there
  LOADZ(zrA, 0, ZA0a, ZA0b, ZA0c, ZA0d)
  LOADZ(zrA, 1, ZA1a, ZA1b, ZA1c, ZA1d)
  if (dual) {
    LOADZ(zrB, 0, ZB0a, ZB0b, ZB0c, ZB0d)
    LOADZ(zrB, 1, ZB1a, ZB1b, ZB1c, ZB1d)
  }
  __builtin_amdgcn_sched_barrier(0);

  // ---- stage Wt quarter: row r (0..127), 16B chunk c stored at c^(r&7)
#pragma unroll
  for (int i = 0; i < 16; ++i) {
    const int id = t + 256 * i;        // 0..4095 chunks
    const int row = id >> 5, c = id & 31;
    ushort8 v = *(const ushort8*)(Wt + (size_t)(n0 + row) * KD + c * 8);
    *(ushort8*)&Bs[row * KD + ((c ^ (row & 7)) << 3)] = v;
  }
  __syncthreads();                     // the ONLY barrier

  f32x4 accA0[8], accA1[8], accB0[8], accB1[8];
#pragma unroll
  for (int f = 0; f < 8; ++f) {
    accA0[f] = (f32x4)0.f; accA1[f] = (f32x4)0.f;
    accB0[f] = (f32x4)0.f; accB1[f] = (f32x4)0.f;
  }

  // one phase = pack current chunk, refill its buffer (kc+2), 8 frags x 2 MFMA
#define PHASE(AC0, AC1, ZP, kc, Ra, Rb, Rc, Rd, PF)                     \
  {                                                                     \
    union { uint4v u; short8 s; } zb0, zb1;                             \
    zb0.u[0] = pkbf(Ra.x, Ra.y); zb0.u[1] = pkbf(Ra.z, Ra.w);           \
    zb0.u[2] = pkbf(Rb.x, Rb.y); zb0.u[3] = pkbf(Rb.z, Rb.w);           \
    zb1.u[0] = pkbf(Rc.x, Rc.y); zb1.u[1] = pkbf(Rc.z, Rc.w);           \
    zb1.u[2] = pkbf(Rd.x, Rd.y); zb1.u[3] = pkbf(Rd.z, Rd.w);           \
    if (PF) { LOADZ(ZP, (kc) + 2, Ra, Rb, Rc, Rd)                       \
              __builtin_amdgcn_sched_barrier(0); }                      \
    _Pragma("unroll")                                                   \
    for (int f = 0; f < 8; ++f) {                                       \
      union { ushort8 u; short8 s; } wv;                                \
      wv.u = *(const ushort8*)&Bs[(f * 16 + l15) * KD +                 \
                                  ((((kc) * 4 + l4) ^ (l15 & 7)) << 3)];\
      AC0[f] = __builtin_amdgcn_mfma_f32_16x16x32_bf16(wv.s, zb0.s, AC0[f], 0, 0, 0); \
      AC1[f] = __builtin_amdgcn_mfma_f32_16x16x32_bf16(wv.s, zb1.s, AC1[f], 0, 0, 0); \
    }                                                                   \
  }

#define PA(kc, Ra, Rb, Rc, Rd, PF) PHASE(accA0, accA1, zrA, kc, Ra, Rb, Rc, Rd, PF)
#define PB(kc, Ra, Rb, Rc, Rd, PF) PHASE(accB0, accB1, zrB, kc, Ra, Rb, Rc, Rd, PF)

  if (dual) {
    PA(0, ZA0a, ZA0b, ZA0c, ZA0d, 1) PB(0, ZB0a, ZB0b, ZB0c, ZB0d, 1)
    PA(1, ZA1a, ZA1b, ZA1c, ZA1d, 1) PB(1, ZB1a, ZB1b, ZB1c, ZB1d, 1)
    PA(2, ZA0a, ZA0b, ZA0c, ZA0d, 1) PB(2, ZB0a, ZB0b, ZB0c, ZB0d, 1)
    PA(3, ZA1a, ZA1b, ZA1c, ZA1d, 1) PB(3, ZB1a, ZB1b, ZB1c, ZB1d, 1)
    PA(4, ZA0a, ZA0b, ZA0c, ZA0d, 1) PB(4, ZB0a, ZB0b, ZB0c, ZB0d, 1)
    PA(5, ZA1a, ZA1b, ZA1c, ZA1d, 1) PB(5, ZB1a, ZB1b, ZB1c, ZB1d, 1)
    PA(6, ZA0a, ZA0b, ZA0c, ZA0d, 0) PB(6, ZB0a, ZB0b, ZB0c, ZB0d, 0)
    PA(7, ZA1a, ZA1b, ZA1c, ZA1d, 0) PB(7, ZB1a, ZB1b, ZB1c, ZB1d, 0)
  } else {
    PA(0, ZA0a, ZA0b, ZA0c, ZA0d, 1)
    PA(1, ZA1a, ZA1b, ZA1c, ZA1d, 1)
    PA(2, ZA0a, ZA0b, ZA0c, ZA0d, 1)
    PA(3, ZA1a, ZA1b, ZA1c, ZA1d, 1)
    PA(4, ZA0a, ZA0b, ZA0c, ZA0d, 1)
    PA(5, ZA1a, ZA1b, ZA1c, ZA1d, 1)
    PA(6, ZA0a, ZA0b, ZA0c, ZA0d, 0)
    PA(7, ZA1a, ZA1b, ZA1c, ZA1d, 0)
  }
#undef PA
#undef PB
#undef PHASE
#undef LOADZ

  // store: lane holds node (l15/band) x wt-cols {n0+f*16+l4*4+0..3}
#define STOREOUT(node0, A0, A1)                                         \
  _Pragma("unroll")                                                     \
  for (int f = 0; f < 8; ++f) {                                         \
    uint2 p;                                                            \
    p.x = pkbf(A0[f][0], A0[f][1]); p.y = pkbf(A0[f][2], A0[f][3]);     \
    *(uint2*)(C + (size_t)((node0) + l15) * NO + n0 + f * 16 + l4 * 4) = p;      \
    p.x = pkbf(A1[f][0], A1[f][1]); p.y = pkbf(A1[f][2], A1[f][3]);     \
    *(uint2*)(C + (size_t)((node0) + 16 + l15) * NO + n0 + f * 16 + l4 * 4) = p; \
  }

  STOREOUT(sA * 32, accA0, accA1)
  if (dual) { STOREOUT(sB * 32, accB0, accB1) }
#undef STOREOUT
}

// ---- per-edge: out[e] = b2 + sum W2[h]*relu(A[s][h] + B[d][h] + b1[h]) ----
__global__ __launch_bounds__(256) void edge_mlp(const unsigned short* __restrict__ C,
                                                const int* __restrict__ ei,
                                                const float* __restrict__ b1,
                                                const float* __restrict__ W2,
                                                const float* __restrict__ b2,
                                                float* __restrict__ out) {
  const int t = threadIdx.x;
  const int lane = t & 63;
  const int g = lane >> 4;           // edge slot within wave (0..3)
  const int c0 = (lane & 15) * 16;   // channel base for this lane
  float b1v[16], w2v[16];
#pragma unroll
  for (int i = 0; i < 16; ++i) { b1v[i] = b1[c0 + i]; w2v[i] = W2[c0 + i]; }
  const float bias2 = b2[0];
  const int waveId = blockIdx.x * 4 + (t >> 6);
  const int nw = gridDim.x * 4;
  for (int e0 = waveId * 4; e0 < NE; e0 += nw * 4) {
    const int e = e0 + g;                 // NE % 4 == 0 -> always valid
    const int sn = ei[e];
    const int dn = ei[NE + e];
    const ushort8* ap = (const ushort8*)(C + (size_t)sn * NO + c0);
    const ushort8* bp = (const ushort8*)(C + (size_t)dn * NO + 256 + c0);
    ushort8 a0 = ap[0], a1 = ap[1];
    ushort8 v0 = bp[0], v1 = bp[1];
    float partial = 0.f;
#pragma unroll
    for (int j = 0; j < 8; ++j) {
      float h = bf2f(a0[j]) + bf2f(v0[j]) + b1v[j];
      h = fmaxf(h, 0.f);
      partial = fmaf(h, w2v[j], partial);
    }
#pragma unroll
    for (int j = 0; j < 8; ++j) {
      float h = bf2f(a1[j]) + bf2f(v1[j]) + b1v[8 + j];
      h = fmaxf(h, 0.f);
      partial = fmaf(h, w2v[8 + j], partial);
    }
    partial += __shfl_xor(partial, 8);
    partial += __shfl_xor(partial, 4);
    partial += __shfl_xor(partial, 2);
    partial += __shfl_xor(partial, 1);
    if ((lane & 15) == 0) out[e] = partial + bias2;
  }
}

extern "C" void kernel_launch(void* const* d_in, const int* in_sizes, int n_in,
                              void* d_out, int out_size, void* d_ws, size_t ws_size,
                              hipStream_t stream) {
  const float* z  = (const float*)d_in[0];
  const float* W1 = (const float*)d_in[1];
  const float* b1 = (const float*)d_in[2];
  const float* W2 = (const float*)d_in[3];
  const float* b2 = (const float*)d_in[4];
  const int*   ei = (const int*)d_in[5];
  float* out = (float*)d_out;

  unsigned short* C  = (unsigned short*)d_ws;          // 100000*512 bf16 = 102.4 MB
  unsigned short* Wt = C + (size_t)NN * NO;            // 512*256 bf16 = 256 KB

  prep_w<<<512, 256, 0, stream>>>(W1, Wt);
  gemm_zw<<<NBLK, 256, 0, stream>>>(z, Wt, C);
  edge_mlp<<<2048, 256, 0, stream>>>(C, ei, b1, W2, b2, out);
}